// Round 1
// baseline (272.523 us; speedup 1.0000x reference)
//
#include <hip/hip_runtime.h>

#define B_  8
#define C_  256
#define L_  4096
#define CO_ 256
#define KD_ 768   // 256 channels * 3 taps, kd = ci*3 + k

typedef __attribute__((ext_vector_type(8))) __bf16 bf16x8;
typedef __attribute__((ext_vector_type(4))) float f32x4;
typedef __attribute__((ext_vector_type(8))) unsigned short u16x8;

__device__ __forceinline__ unsigned short f2bf(float f){
  union { float f; unsigned u; } v; v.f = f;
  unsigned r = v.u + 0x7fffu + ((v.u >> 16) & 1u);   // RNE
  return (unsigned short)(r >> 16);
}
__device__ __forceinline__ float bf2f(unsigned short h){
  union { unsigned u; float f; } v; v.u = ((unsigned)h) << 16;
  return v.f;
}

// XOR-swizzled u16 index into a [64][192] bf16 tile (row stride 384B).
// Swizzle flips u16-index bits 3..5 (byte bits 4..6): breaks the 16-way
// bank conflict on ds_read_b128 column reads; 192 cols = 24 chunks of 8,
// complete groups of 8 -> XOR stays in-row. 16B alignment preserved.
__device__ __forceinline__ int sw(int row, int col){
  return row * 192 + (col ^ ((row & 7) << 3));
}

// ---------------- x transpose + bf16: xT[b][l][ci] ----------------
__global__ __launch_bounds__(256) void xpose_kernel(const float* __restrict__ x,
                                                    unsigned short* __restrict__ xT){
  __shared__ unsigned short tile[64][66];   // +2 pad: bank = (33c + l/2)%32, spread
  int l0 = blockIdx.x * 64, c0 = blockIdx.y * 64, b = blockIdx.z;
  const float* xb = x + (size_t)b * C_ * L_;
  unsigned short* xTb = xT + (size_t)b * L_ * C_;
  int tj  = threadIdx.x & 63;
  int ti0 = threadIdx.x >> 6;
  #pragma unroll
  for (int i = ti0; i < 64; i += 4)
    tile[i][tj] = f2bf(xb[(size_t)(c0 + i) * L_ + l0 + tj]);   // coalesced along l
  __syncthreads();
  #pragma unroll
  for (int i = ti0; i < 64; i += 4)
    xTb[(size_t)(l0 + i) * C_ + c0 + tj] = tile[tj][i];        // coalesced along c
}

// ---------------- stage 1: off[b][c][l] = conv1d(x, offset_w) + offset_b ----
// GEMM: D[c][l] = sum_kd A[c][kd] * Bt[l][kd], A = offset_w flat [256][768]
template <bool USE_XT>
__global__ __launch_bounds__(256) void off_gemm(const float* __restrict__ x,
                                                const float* __restrict__ offw,
                                                const float* __restrict__ offb,
                                                const unsigned short* __restrict__ xT,
                                                unsigned short* __restrict__ off_out){
  __shared__ __align__(16) unsigned short As[64 * 192];
  __shared__ __align__(16) unsigned short Bs[64 * 192];
  int l0 = blockIdx.x * 64, c0 = blockIdx.y * 64, b = blockIdx.z;
  int t = threadIdx.x;
  int lane = t & 63, wid = t >> 6;
  int wm = wid >> 1, wn = wid & 1;
  f32x4 acc[2][2] = {};
  const unsigned short* xTb = xT + (size_t)b * L_ * C_;
  const float* xb = x + (size_t)b * C_ * L_;

  for (int ch = 0; ch < 4; ++ch){
    int kc0 = ch * 192;
    int ci0 = ch * 64;
    // ---- As: rows = 64 output channels, cols = 192 kd (offset_w fp32 -> bf16)
    {
      int row = t >> 2, seg = t & 3;   // 4 lanes share one row: 192B contig per row
      const float4* src = reinterpret_cast<const float4*>(
          offw + (size_t)(c0 + row) * KD_ + kc0 + seg * 48);
      #pragma unroll
      for (int u = 0; u < 6; ++u){
        float4 v0 = src[2*u], v1 = src[2*u+1];
        u16x8 h;
        h[0]=f2bf(v0.x); h[1]=f2bf(v0.y); h[2]=f2bf(v0.z); h[3]=f2bf(v0.w);
        h[4]=f2bf(v1.x); h[5]=f2bf(v1.y); h[6]=f2bf(v1.z); h[7]=f2bf(v1.w);
        *reinterpret_cast<u16x8*>(&As[sw(row, seg * 48 + u * 8)]) = h;
      }
    }
    // ---- Bs: rows = 64 l, cols kd_local = (ci-ci0)*3+k, value x[b][ci][l+k-1]
    {
      int ci  = t & 63;    // lane = ci: xT row reads are 128B contiguous
      int lr0 = t >> 6;
      #pragma unroll
      for (int i = 0; i < 16; ++i){
        int lr = lr0 * 16 + i;
        #pragma unroll
        for (int k = 0; k < 3; ++k){
          int sl = l0 + lr + k - 1;
          unsigned short v = 0;
          if (sl >= 0 && sl < L_)
            v = USE_XT ? xTb[(size_t)sl * C_ + ci0 + ci]
                       : f2bf(xb[(size_t)(ci0 + ci) * L_ + sl]);
          Bs[sw(lr, ci * 3 + k)] = v;
        }
      }
    }
    __syncthreads();
    // ---- MFMA: 6 k-frags x 2m x 2n
    #pragma unroll
    for (int kf = 0; kf < 6; ++kf){
      int col = kf * 32 + (lane >> 4) * 8;
      bf16x8 afr[2], bfr[2];
      #pragma unroll
      for (int mi = 0; mi < 2; ++mi)
        afr[mi] = __builtin_bit_cast(bf16x8,
          *reinterpret_cast<const u16x8*>(&As[sw(wm*32 + mi*16 + (lane & 15), col)]));
      #pragma unroll
      for (int ni = 0; ni < 2; ++ni)
        bfr[ni] = __builtin_bit_cast(bf16x8,
          *reinterpret_cast<const u16x8*>(&Bs[sw(wn*32 + ni*16 + (lane & 15), col)]));
      #pragma unroll
      for (int mi = 0; mi < 2; ++mi)
        #pragma unroll
        for (int ni = 0; ni < 2; ++ni)
          acc[mi][ni] = __builtin_amdgcn_mfma_f32_16x16x32_bf16(afr[mi], bfr[ni], acc[mi][ni], 0, 0, 0);
    }
    __syncthreads();
  }
  // ---- epilogue: + offset_b, store bf16 off[b][c][l]
  unsigned short* ob = off_out + (size_t)b * C_ * L_;
  int rg = lane >> 4, cx = lane & 15;
  #pragma unroll
  for (int mi = 0; mi < 2; ++mi)
    #pragma unroll
    for (int ni = 0; ni < 2; ++ni)
      #pragma unroll
      for (int r = 0; r < 4; ++r){
        int c = c0 + wm*32 + mi*16 + rg*4 + r;
        int l = l0 + wn*32 + ni*16 + cx;
        ob[(size_t)c * L_ + l] = f2bf(acc[mi][ni][r] + offb[c]);
      }
}

// ---------------- stage 2: sample + main GEMM + bias -> out fp32 ----------
__global__ __launch_bounds__(256) void main_gemm(const float* __restrict__ x,
                                                 const float* __restrict__ w,
                                                 const float* __restrict__ bias,
                                                 const unsigned short* __restrict__ off_in,
                                                 float* __restrict__ out){
  __shared__ __align__(16) unsigned short As[64 * 192];
  __shared__ __align__(16) unsigned short Bs[64 * 192];
  int l0 = blockIdx.x * 64, o0 = blockIdx.y * 64, b = blockIdx.z;
  int t = threadIdx.x;
  int lane = t & 63, wid = t >> 6;
  int wm = wid >> 1, wn = wid & 1;
  f32x4 acc[2][2] = {};
  const float* xb = x + (size_t)b * C_ * L_;
  const unsigned short* offp = off_in + (size_t)b * C_ * L_;

  for (int ch = 0; ch < 4; ++ch){
    int kc0  = ch * 192;
    int cin0 = ch * 64;
    // ---- As: rows = 64 output channels o, cols = 192 kd (weight fp32 -> bf16)
    {
      int row = t >> 2, seg = t & 3;
      const float4* src = reinterpret_cast<const float4*>(
          w + (size_t)(o0 + row) * KD_ + kc0 + seg * 48);
      #pragma unroll
      for (int u = 0; u < 6; ++u){
        float4 v0 = src[2*u], v1 = src[2*u+1];
        u16x8 h;
        h[0]=f2bf(v0.x); h[1]=f2bf(v0.y); h[2]=f2bf(v0.z); h[3]=f2bf(v0.w);
        h[4]=f2bf(v1.x); h[5]=f2bf(v1.y); h[6]=f2bf(v1.z); h[7]=f2bf(v1.w);
        *reinterpret_cast<u16x8*>(&As[sw(row, seg * 48 + u * 8)]) = h;
      }
    }
    // ---- Bs: rows = 64 l, cols = (c-cin0)*3+k = sampled[b][c][k][l] (bf16)
    // One offset serves all 3 taps: pos_k = (l-1+off)+k, same frac w1,
    // 4 consecutive x values -> 3 sampled values.
    {
      int ll = t & 63;    // lane = l: off reads coalesced, x gathers near-sequential
      int cg = t >> 6;
      int lg = l0 + ll;
      #pragma unroll
      for (int i = 0; i < 16; ++i){
        int cc = cg * 16 + i;
        int c  = cin0 + cc;
        float off = bf2f(offp[(size_t)c * L_ + lg]);
        float pos = (float)(lg - 1) + off;
        float p0  = floorf(pos);
        float w1  = pos - p0;
        int   i0  = (int)p0;
        const float* xr = xb + (size_t)c * L_;
        float v[4];
        #pragma unroll
        for (int j = 0; j < 4; ++j){
          int idx = i0 + j;
          v[j] = (idx >= 0 && idx < L_) ? xr[idx] : 0.0f;
        }
        #pragma unroll
        for (int k = 0; k < 3; ++k){
          float s = v[k] * (1.0f - w1) + v[k+1] * w1;
          Bs[sw(ll, cc * 3 + k)] = f2bf(s);
        }
      }
    }
    __syncthreads();
    // ---- MFMA
    #pragma unroll
    for (int kf = 0; kf < 6; ++kf){
      int col = kf * 32 + (lane >> 4) * 8;
      bf16x8 afr[2], bfr[2];
      #pragma unroll
      for (int mi = 0; mi < 2; ++mi)
        afr[mi] = __builtin_bit_cast(bf16x8,
          *reinterpret_cast<const u16x8*>(&As[sw(wm*32 + mi*16 + (lane & 15), col)]));
      #pragma unroll
      for (int ni = 0; ni < 2; ++ni)
        bfr[ni] = __builtin_bit_cast(bf16x8,
          *reinterpret_cast<const u16x8*>(&Bs[sw(wn*32 + ni*16 + (lane & 15), col)]));
      #pragma unroll
      for (int mi = 0; mi < 2; ++mi)
        #pragma unroll
        for (int ni = 0; ni < 2; ++ni)
          acc[mi][ni] = __builtin_amdgcn_mfma_f32_16x16x32_bf16(afr[mi], bfr[ni], acc[mi][ni], 0, 0, 0);
    }
    __syncthreads();
  }
  // ---- epilogue: + bias, store fp32 out[b][o][l]
  float* ob = out + (size_t)b * CO_ * L_;
  int rg = lane >> 4, cx = lane & 15;
  #pragma unroll
  for (int mi = 0; mi < 2; ++mi)
    #pragma unroll
    for (int ni = 0; ni < 2; ++ni)
      #pragma unroll
      for (int r = 0; r < 4; ++r){
        int o = o0 + wm*32 + mi*16 + rg*4 + r;
        int l = l0 + wn*32 + ni*16 + cx;
        ob[(size_t)o * L_ + l] = acc[mi][ni][r] + bias[o];
      }
}

extern "C" void kernel_launch(void* const* d_in, const int* in_sizes, int n_in,
                              void* d_out, int out_size, void* d_ws, size_t ws_size,
                              hipStream_t stream){
  (void)in_sizes; (void)n_in; (void)out_size;
  const float* x   = (const float*)d_in[0];
  const float* ow  = (const float*)d_in[1];
  const float* obv = (const float*)d_in[2];
  const float* w   = (const float*)d_in[3];
  const float* bv  = (const float*)d_in[4];
  float* out = (float*)d_out;

  unsigned short* off_ws = (unsigned short*)d_ws;                     // 16 MB bf16 off[b][c][l]
  unsigned short* xT     = off_ws + (size_t)B_ * C_ * L_;             // 16 MB bf16 xT[b][l][c]
  size_t need_xt = (size_t)B_ * C_ * L_ * 2u * 2u;                    // off + xT

  dim3 blk(256);
  dim3 grd(L_ / 64, C_ / 64, B_);
  if (ws_size >= need_xt){
    xpose_kernel<<<grd, blk, 0, stream>>>(x, xT);
    off_gemm<true><<<grd, blk, 0, stream>>>(x, ow, obv, xT, off_ws);
  } else {
    off_gemm<false><<<grd, blk, 0, stream>>>(x, ow, obv, xT, off_ws);
  }
  main_gemm<<<grd, blk, 0, stream>>>(x, w, bv, off_ws, out);
}

// Round 2
// 103.816 us; speedup vs baseline: 2.6251x; 2.6251x over previous
//
#include <hip/hip_runtime.h>

#define B_  8
#define C_  256
#define L_  4096
#define KD_ 768   // 256 ci * 3 taps

typedef __attribute__((ext_vector_type(8))) __bf16 bf16x8;
typedef __attribute__((ext_vector_type(4))) float f32x4;
typedef __attribute__((ext_vector_type(8))) unsigned short u16x8;

__device__ __forceinline__ unsigned short f2bf(float f){
  union { float f; unsigned u; } v; v.f = f;
  unsigned r = v.u + 0x7fffu + ((v.u >> 16) & 1u);   // RNE
  return (unsigned short)(r >> 16);
}
__device__ __forceinline__ float bf2f(unsigned short h){
  union { unsigned u; float f; } v; v.u = ((unsigned)h) << 16;
  return v.f;
}

// Swizzled u16 index in a [rows][128] u16 tile (row stride 256B).
// XOR col bits 3..5 with row bits 0..2: ds_read_b128 column reads go from
// 16-way conflict (256B stride = same bank) to 2-way (free, m136).
__device__ __forceinline__ int swz(int row, int col){
  return (row << 7) + (col ^ ((row & 7) << 3));
}

// async global->LDS, 16B per lane, 1KB per wave-issue. LDS dest is
// wave-uniform base + lane*16 (linear); source is per-lane.
__device__ __forceinline__ void stage_tile32k(const unsigned short* __restrict__ g,
                                              unsigned short* l, int t){
  int wid = t >> 6, lane = t & 63;
  #pragma unroll
  for (int s = 0; s < 4; ++s){
    int seg = wid * 4 + s;                       // 32 segments of 1KB
    const char* src = (const char*)g + seg * 1024 + lane * 16;
    char* dst = (char*)l + seg * 1024;
    __builtin_amdgcn_global_load_lds(
        (const __attribute__((address_space(1))) unsigned int*)src,
        (__attribute__((address_space(3))) unsigned int*)dst, 16, 0, 0);
  }
}

// ---------------- prep: both weight tensors -> bf16 swizzled 128x128 tiles ----
// wO tiles: [ct2][cih2][k3][128 rows c][128 cols ci]   (k-major chunks)
// wM tiles: [ot2][ch8][128 rows o][col = kd%96, pad to 128]  (kd = ci*3+k natural)
__global__ __launch_bounds__(256) void prep_w(const float* __restrict__ offw,
                                              const float* __restrict__ w,
                                              unsigned short* __restrict__ wO,
                                              unsigned short* __restrict__ wM){
  int idx = blockIdx.x * 256 + threadIdx.x;
  if (idx >= 256 * KD_) return;
  int r = idx / KD_, rem = idx % KD_;
  int row = r & 127, rt = r >> 7;
  {           // offset-conv weights: rem = ci*3 + k
    int ci = rem / 3, k = rem % 3;
    int tile = (rt * 2 + (ci >> 7)) * 3 + k;
    wO[tile * 16384 + swz(row, ci & 127)] = f2bf(offw[idx]);
  }
  {           // main weights: chunks of 96 kd, padded to 128 cols
    int ch = rem / 96, col = rem % 96;
    int tile = rt * 8 + ch;
    wM[tile * 16384 + swz(row, col)] = f2bf(w[idx]);
  }
}

// ---------------- stage 1: off[b][c][l] = conv1d(x, offset_w) + offset_b ------
// D[c][l] = sum_{k,ci} A[c][k*256+ci] * x[ci][l+k-1]
// B-operand = Xs (transposed x slab) read with row shift +k: no im2col copy.
__global__ __launch_bounds__(512, 4) void off_gemm(const float* __restrict__ x,
                                                   const unsigned short* __restrict__ wO,
                                                   const float* __restrict__ offb,
                                                   unsigned short* __restrict__ off_out){
  __shared__ __align__(16) unsigned short As[16384];       // 32KB: 128 c x 128 ci
  __shared__ __align__(16) unsigned short Xs[130 * 128];   // 33.3KB: 130 l x 128 ci
  int l0 = blockIdx.x * 128, c0 = blockIdx.y * 128, b = blockIdx.z;
  int ct = blockIdx.y;
  int t = threadIdx.x, lane = t & 63, wid = t >> 6;
  int wm = wid >> 1, wn = wid & 1;            // wave tile: 32 c x 64 l
  const float* xb = x + (size_t)b * C_ * L_;
  f32x4 acc[2][4] = {};

  for (int cih = 0; cih < 2; ++cih){
    __syncthreads();                          // prior MFMA done reading Xs
    // stage Xs: lrow -> l = l0+lrow-1, coalesced fp32 reads (lane = l)
    for (int cc = wid; cc < 128; cc += 8){
      const float* xr = xb + (size_t)(cih * 128 + cc) * L_;
      for (int lb = 0; lb < 130; lb += 64){
        int lrow = lb + lane;
        if (lrow < 130){
          int l = l0 + lrow - 1;
          unsigned short v = (l >= 0 && l < L_) ? f2bf(xr[l]) : (unsigned short)0;
          Xs[swz(lrow, cc)] = v;
        }
      }
    }
    for (int k = 0; k < 3; ++k){
      stage_tile32k(wO + (size_t)((ct * 2 + cih) * 3 + k) * 16384, As, t);
      __syncthreads();
      #pragma unroll
      for (int kf = 0; kf < 4; ++kf){
        int col = kf * 32 + (lane >> 4) * 8;
        bf16x8 af[2], bfr[4];
        #pragma unroll
        for (int mi = 0; mi < 2; ++mi)
          af[mi] = __builtin_bit_cast(bf16x8,
            *reinterpret_cast<const u16x8*>(&As[swz(wm*32 + mi*16 + (lane & 15), col)]));
        #pragma unroll
        for (int ni = 0; ni < 4; ++ni)
          bfr[ni] = __builtin_bit_cast(bf16x8,
            *reinterpret_cast<const u16x8*>(&Xs[swz(wn*64 + ni*16 + (lane & 15) + k, col)]));
        #pragma unroll
        for (int mi = 0; mi < 2; ++mi)
          #pragma unroll
          for (int ni = 0; ni < 4; ++ni)
            acc[mi][ni] = __builtin_amdgcn_mfma_f32_16x16x32_bf16(af[mi], bfr[ni], acc[mi][ni], 0, 0, 0);
      }
      __syncthreads();
    }
  }
  // epilogue: + offset_b, store bf16 off[b][c][l]
  unsigned short* ob = off_out + (size_t)b * C_ * L_;
  int rg = lane >> 4, cx = lane & 15;
  #pragma unroll
  for (int mi = 0; mi < 2; ++mi)
    #pragma unroll
    for (int r = 0; r < 4; ++r){
      int c = c0 + wm*32 + mi*16 + rg*4 + r;
      float bv = offb[c];
      #pragma unroll
      for (int ni = 0; ni < 4; ++ni){
        int l = l0 + wn*64 + ni*16 + cx;
        ob[(size_t)c * L_ + l] = f2bf(acc[mi][ni][r] + bv);
      }
    }
}

// ---------------- stage 2: sample + main GEMM + bias -> out fp32 --------------
__global__ __launch_bounds__(512, 4) void main_gemm(const float* __restrict__ x,
                                                    const unsigned short* __restrict__ wM,
                                                    const float* __restrict__ bias,
                                                    const unsigned short* __restrict__ off_in,
                                                    float* __restrict__ out){
  __shared__ __align__(16) unsigned short As[16384];   // 128 o x (96 kd pad 128)
  __shared__ __align__(16) unsigned short Bs[16384];   // 128 l x (96 kd pad 128)
  int l0 = blockIdx.x * 128, o0 = blockIdx.y * 128, b = blockIdx.z;
  int t = threadIdx.x, lane = t & 63, wid = t >> 6;
  int wm = wid >> 1, wn = wid & 1;            // wave tile: 32 o x 64 l
  const float* xb = x + (size_t)b * C_ * L_;
  const unsigned short* offp = off_in + (size_t)b * C_ * L_;
  f32x4 acc[2][4] = {};

  for (int ch = 0; ch < 8; ++ch){
    int cin0 = ch * 32;
    stage_tile32k(wM + (size_t)(blockIdx.y * 8 + ch) * 16384, As, t);
    // sample 128 l x 32 ci, one offset serves 3 taps (4 x-reads -> 3 values)
    #pragma unroll
    for (int it = 0; it < 8; ++it){
      int e = it * 512 + t;                   // 0..4095
      int lrow = e & 127, cc = e >> 7;        // lane-consecutive l: coalesced
      int cg = cin0 + cc;
      int l = l0 + lrow;
      float off = bf2f(offp[(size_t)cg * L_ + l]);
      float pos = (float)(l - 1) + off;
      float p0  = floorf(pos);
      float w1  = pos - p0;
      int   i0  = (int)p0;
      const float* xr = xb + (size_t)cg * L_;
      float v[4];
      #pragma unroll
      for (int j = 0; j < 4; ++j){
        int idx = i0 + j;
        v[j] = (idx >= 0 && idx < L_) ? xr[idx] : 0.0f;
      }
      #pragma unroll
      for (int k = 0; k < 3; ++k)
        Bs[swz(lrow, cc * 3 + k)] = f2bf(v[k] * (1.0f - w1) + v[k+1] * w1);
    }
    __syncthreads();
    #pragma unroll
    for (int kf = 0; kf < 3; ++kf){           // 96 kd per chunk
      int col = kf * 32 + (lane >> 4) * 8;
      bf16x8 af[2], bfr[4];
      #pragma unroll
      for (int mi = 0; mi < 2; ++mi)
        af[mi] = __builtin_bit_cast(bf16x8,
          *reinterpret_cast<const u16x8*>(&As[swz(wm*32 + mi*16 + (lane & 15), col)]));
      #pragma unroll
      for (int ni = 0; ni < 4; ++ni)
        bfr[ni] = __builtin_bit_cast(bf16x8,
          *reinterpret_cast<const u16x8*>(&Bs[swz(wn*64 + ni*16 + (lane & 15), col)]));
      #pragma unroll
      for (int mi = 0; mi < 2; ++mi)
        #pragma unroll
        for (int ni = 0; ni < 4; ++ni)
          acc[mi][ni] = __builtin_amdgcn_mfma_f32_16x16x32_bf16(af[mi], bfr[ni], acc[mi][ni], 0, 0, 0);
    }
    __syncthreads();
  }
  // epilogue: + bias, fp32 out[b][o][l]
  float* ob = out + (size_t)b * C_ * L_;
  int rg = lane >> 4, cx = lane & 15;
  #pragma unroll
  for (int mi = 0; mi < 2; ++mi)
    #pragma unroll
    for (int r = 0; r < 4; ++r){
      int o = o0 + wm*32 + mi*16 + rg*4 + r;
      float bv = bias[o];
      #pragma unroll
      for (int ni = 0; ni < 4; ++ni){
        int l = l0 + wn*64 + ni*16 + cx;
        ob[(size_t)o * L_ + l] = acc[mi][ni][r] + bv;
      }
    }
}

extern "C" void kernel_launch(void* const* d_in, const int* in_sizes, int n_in,
                              void* d_out, int out_size, void* d_ws, size_t ws_size,
                              hipStream_t stream){
  (void)in_sizes; (void)n_in; (void)out_size; (void)ws_size;
  const float* x   = (const float*)d_in[0];
  const float* ow  = (const float*)d_in[1];
  const float* obv = (const float*)d_in[2];
  const float* w   = (const float*)d_in[3];
  const float* bv  = (const float*)d_in[4];
  float* out = (float*)d_out;

  unsigned short* wO     = (unsigned short*)d_ws;     // 2*2*3*16384 u16 = 384KB
  unsigned short* wM     = wO + 2*2*3*16384;          // 2*8*16384 u16   = 512KB
  unsigned short* off_ws = wM + 2*8*16384;            // 8M u16 = 16MB
  // total 17.7MB (ws known >= 32MB from round-1 xT path)

  prep_w<<<dim3((256 * KD_ + 255) / 256), dim3(256), 0, stream>>>(ow, w, wO, wM);
  dim3 blk(512);
  dim3 grd(L_ / 128, C_ / 128, B_);
  off_gemm<<<grd, blk, 0, stream>>>(x, wO, obv, off_ws);
  main_gemm<<<grd, blk, 0, stream>>>(x, wM, bv, off_ws, out);
}